// Round 1
// baseline (586.208 us; speedup 1.0000x reference)
//
#include <hip/hip_runtime.h>
#include <hip/hip_bf16.h>

#define BB 2
#define LL 2048
#define DD 1024
#define HH 16
#define HD 64

typedef __attribute__((ext_vector_type(8))) short short8;
typedef __attribute__((ext_vector_type(4))) float f32x4;

__device__ __forceinline__ short f2b(float f) {
    __hip_bfloat16 h = __float2bfloat16(f);
    union { __hip_bfloat16 h; short s; } u;
    u.h = h;
    return u.s;
}

// ---------------------------------------------------------------------------
// Kernel 1: convert x, Wq, Wk, Wv, Wo (f32) -> bf16 workspace (contiguous)
// layout (elements): xb[4194304] wqb[1048576] wkb[1048576] wvb[1048576] wob[1048576]
// ---------------------------------------------------------------------------
__global__ __launch_bounds__(256) void cvt_all(
    const float* __restrict__ x,  const float* __restrict__ wq,
    const float* __restrict__ wk, const float* __restrict__ wv,
    const float* __restrict__ wo, short* __restrict__ ws)
{
    int i4 = blockIdx.x * 256 + threadIdx.x;       // one float4 per thread
    if (i4 >= 2097152) return;                     // 8,388,608 / 4
    long i = (long)i4 * 4;
    const float* src;
    if (i < 4194304) {
        src = x + i;
    } else {
        long j = i - 4194304;
        int  w = (int)(j >> 20);
        long o = j & 1048575;
        src = (w == 0 ? wq : w == 1 ? wk : w == 2 ? wv : wo) + o;
    }
    float4 v = *(const float4*)src;
    short4 r;
    r.x = f2b(v.x); r.y = f2b(v.y); r.z = f2b(v.z); r.w = f2b(v.w);
    *(short4*)(ws + i) = r;
}

// ---------------------------------------------------------------------------
// Kernel 2: NT GEMM  C[m,n] = sum_k A[m,k] * Bm[n,k], A/Bm bf16 row-major K=1024
// 64x64 tile, BK=32, 256 threads (4 waves), each wave: 64 rows x 16 cols.
// mode 0: Out bf16 [B,H,L,HD]   (Q,K)
// mode 1: Out bf16 [B,H,HD,L]   (V transposed)
// mode 3: Out f32  row-major [M,1024]  (final output)
// ---------------------------------------------------------------------------
__global__ __launch_bounds__(256) void gemm_nt(
    const short* __restrict__ A, const short* __restrict__ Bm,
    void* __restrict__ Out, int mode)
{
    __shared__ __align__(16) short As[64][40];
    __shared__ __align__(16) short Bs[64][40];

    const int tid  = threadIdx.x;
    const int wave = tid >> 6;
    const int lane = tid & 63;
    const int r16  = lane & 15;
    const int g4   = lane >> 4;
    const int m0   = blockIdx.x * 64;
    const int n0   = blockIdx.y * 64;

    const int srow = tid >> 2;          // 0..63
    const int scol = (tid & 3) * 8;     // 0,8,16,24

    f32x4 acc[4] = {};

    for (int k0 = 0; k0 < 1024; k0 += 32) {
        __syncthreads();
        *(short8*)&As[srow][scol] = *(const short8*)&A [(long)(m0 + srow) * 1024 + k0 + scol];
        *(short8*)&Bs[srow][scol] = *(const short8*)&Bm[(long)(n0 + srow) * 1024 + k0 + scol];
        __syncthreads();

        short8 bf = *(const short8*)&Bs[wave * 16 + r16][g4 * 8];
#pragma unroll
        for (int m = 0; m < 4; ++m) {
            short8 af = *(const short8*)&As[m * 16 + r16][g4 * 8];
            acc[m] = __builtin_amdgcn_mfma_f32_16x16x32_bf16(af, bf, acc[m], 0, 0, 0);
        }
    }

#pragma unroll
    for (int m = 0; m < 4; ++m) {
        const int gcol = n0 + wave * 16 + r16;
#pragma unroll
        for (int j = 0; j < 4; ++j) {
            const int grow = m0 + m * 16 + g4 * 4 + j;
            float v = acc[m][j];
            if (mode == 3) {
                ((float*)Out)[(long)grow * 1024 + gcol] = v;
            } else {
                short s = f2b(v);
                int b = grow >> 11, l = grow & 2047;
                int h = gcol >> 6,  hd = gcol & 63;
                long idx = (mode == 0)
                    ? (((long)(b * HH + h) * LL + l) * HD + hd)
                    : (((long)(b * HH + h) * HD + hd) * LL + l);
                ((short*)Out)[idx] = s;
            }
        }
    }
}

// ---------------------------------------------------------------------------
// Kernel 3: causal sparsemax attention.
// Block = one (b,h) x 16 q-rows. 16 waves (1024 threads).
// Phase 1: QK^T via MFMA (Q,K frags straight from global), scores -> LDS f32.
// Phase 2: wave r = row r: Michelot fixed-point tau; p = max(z-tau,0) -> LDS;
//          per-32-key-tile nonzero flags.
// Phase 3: waves 0..3: PV MFMA over nonzero tiles only; write AO bf16 [B,L,D].
// ---------------------------------------------------------------------------
__global__ __launch_bounds__(1024) void attn_sparsemax(
    const short* __restrict__ Q, const short* __restrict__ K,
    const short* __restrict__ Vt, short* __restrict__ AO)
{
    __shared__ __align__(16) float S[16][2052];
    __shared__ unsigned flags[64];

    const int tid  = threadIdx.x;
    const int wave = tid >> 6;
    const int lane = tid & 63;
    const int r16  = lane & 15;
    const int g4   = lane >> 4;

    const int blk = blockIdx.x;
    const int qt  = blk & 127;       // q-tile within (b,h)
    const int bh  = blk >> 7;        // 0..31
    const int q0  = qt * 16;

    if (tid < 64) flags[tid] = 0;

    // Q fragments (A operand), loaded once: rows q0..q0+15, k-halves 0/1
    const long qbase = ((long)bh * LL + q0 + r16) * HD + g4 * 8;
    const short8 qa0 = *(const short8*)&Q[qbase];
    const short8 qa1 = *(const short8*)&Q[qbase + 32];

    // ---- Phase 1: QK^T ----
    for (int kt = wave; kt <= qt; kt += 16) {
        const long kbase = ((long)bh * LL + kt * 16 + r16) * HD + g4 * 8;
        short8 kb0 = *(const short8*)&K[kbase];
        short8 kb1 = *(const short8*)&K[kbase + 32];
        f32x4 sc = {};
        sc = __builtin_amdgcn_mfma_f32_16x16x32_bf16(qa0, kb0, sc, 0, 0, 0);
        sc = __builtin_amdgcn_mfma_f32_16x16x32_bf16(qa1, kb1, sc, 0, 0, 0);
        const int key = kt * 16 + r16;
#pragma unroll
        for (int j = 0; j < 4; ++j) {
            const int qrow = g4 * 4 + j;
            float v = sc[j] * 0.125f;            // 1/sqrt(64)
            if (key > q0 + qrow) v = -1e9f;      // causal mask
            S[qrow][key] = v;
        }
    }
    __syncthreads();

    // ---- Phase 2: sparsemax, wave r handles row r ----
    {
        const int r   = wave;
        const int len = q0 + r + 1;              // valid prefix length
        float z[32];
#pragma unroll
        for (int j = 0; j < 32; ++j) {
            const int k = j * 64 + lane;
            const float zz = S[r][k];            // uninit beyond computed region is OK
            z[j] = (k < len) ? zz : -1e30f;
        }
        float tau = -3e28f;
        int cprev = -1;
        for (int it = 0; it < 40; ++it) {
            float s = 0.f; int c = 0;
#pragma unroll
            for (int j = 0; j < 32; ++j) {
                if (z[j] > tau) { s += z[j]; c++; }
            }
#pragma unroll
            for (int o = 32; o; o >>= 1) {
                s += __shfl_xor(s, o);
                c += __shfl_xor(c, o);
            }
            if (c == cprev) break;               // support stable -> converged
            tau = (s - 1.0f) / (float)c;
            cprev = c;
        }
#pragma unroll
        for (int j = 0; j < 32; ++j) {
            const int k = j * 64 + lane;
            float p = z[j] - tau;
            p = p > 0.f ? p : 0.f;
            S[r][k] = p;                          // overwrite scores with probs (f32)
            unsigned long long m = __ballot(p > 0.f);
            if (lane == 0) {
                if (m & 0xffffffffull) atomicOr(&flags[2 * j], 1u);
                if (m >> 32)           atomicOr(&flags[2 * j + 1], 1u);
            }
        }
    }
    __syncthreads();

    // ---- Phase 3: PV, waves 0..3 (wave = d-tile), skip all-zero key tiles ----
    if (wave < 4) {
        const int nkt = (q0 + 16 + 31) >> 5;
        f32x4 acc = {};
        for (int kt = 0; kt < nkt; ++kt) {
            if (!flags[kt]) continue;
            const int kb = kt * 32 + g4 * 8;
            f32x4 p0 = *(const f32x4*)&S[r16][kb];
            f32x4 p1 = *(const f32x4*)&S[r16][kb + 4];
            short8 pa;
            pa[0] = f2b(p0[0]); pa[1] = f2b(p0[1]); pa[2] = f2b(p0[2]); pa[3] = f2b(p0[3]);
            pa[4] = f2b(p1[0]); pa[5] = f2b(p1[1]); pa[6] = f2b(p1[2]); pa[7] = f2b(p1[3]);
            short8 vb = *(const short8*)&Vt[((long)bh * HD + wave * 16 + r16) * LL + kb];
            acc = __builtin_amdgcn_mfma_f32_16x16x32_bf16(pa, vb, acc, 0, 0, 0);
        }
        const int b = bh >> 4, h = bh & 15;
#pragma unroll
        for (int j = 0; j < 4; ++j) {
            const int qrow = g4 * 4 + j;
            const long idx = ((long)b * LL + q0 + qrow) * DD + h * HD + wave * 16 + r16;
            AO[idx] = f2b(acc[j]);
        }
    }
}

// ---------------------------------------------------------------------------
extern "C" void kernel_launch(void* const* d_in, const int* in_sizes, int n_in,
                              void* d_out, int out_size, void* d_ws, size_t ws_size,
                              hipStream_t stream)
{
    const float* x  = (const float*)d_in[0];
    const float* wq = (const float*)d_in[1];
    const float* wk = (const float*)d_in[2];
    const float* wv = (const float*)d_in[3];
    const float* wo = (const float*)d_in[4];

    short* ws  = (short*)d_ws;
    short* xb  = ws;                     // 4,194,304 elems
    short* wqb = ws + 4194304;           // 1,048,576
    // wkb = ws + 5242880, wvb = ws + 6291456, wob = ws + 7340032 (contiguous)
    short* wkb = ws + 5242880;
    short* wvb = ws + 6291456;
    short* wob = ws + 7340032;
    short* Qb  = ws + 8388608;           // [B,H,L,HD]   4,194,304
    short* Kb  = ws + 12582912;          // [B,H,L,HD]
    short* Vtb = ws + 16777216;          // [B,H,HD,L]
    short* AOb = ws + 20971520;          // [B*L, D] bf16

    cvt_all<<<8192, 256, 0, stream>>>(x, wq, wk, wv, wo, ws);

    dim3 g(64, 16);
    gemm_nt<<<g, 256, 0, stream>>>(xb, wqb, Qb, 0);
    gemm_nt<<<g, 256, 0, stream>>>(xb, wkb, Kb, 0);
    gemm_nt<<<g, 256, 0, stream>>>(xb, wvb, Vtb, 1);

    attn_sparsemax<<<4096, 1024, 0, stream>>>(Qb, Kb, Vtb, AOb);

    gemm_nt<<<g, 256, 0, stream>>>(AOb, wob, (void*)d_out, 3);
}

// Round 4
// 377.814 us; speedup vs baseline: 1.5516x; 1.5516x over previous
//
#include <hip/hip_runtime.h>
#include <hip/hip_bf16.h>

#define LL 2048
#define DD 1024
#define HH 16
#define HD 64

typedef __attribute__((ext_vector_type(8))) short short8;
typedef __attribute__((ext_vector_type(4))) float f32x4;
typedef unsigned int u32;
typedef __attribute__((address_space(3))) u32 lds_u32;
typedef const __attribute__((address_space(1))) u32 glb_u32;

__device__ __forceinline__ short f2b(float f) {
    union { __hip_bfloat16 h; short s; } u;
    u.h = __float2bfloat16(f);
    return u.s;
}

// ---------------------------------------------------------------------------
// Kernel 1: convert x, Wq, Wk, Wv, Wo (f32) -> bf16 workspace (contiguous)
// ---------------------------------------------------------------------------
__global__ __launch_bounds__(256) void cvt_all(
    const float* __restrict__ x,  const float* __restrict__ wq,
    const float* __restrict__ wk, const float* __restrict__ wv,
    const float* __restrict__ wo, short* __restrict__ ws)
{
    int i4 = blockIdx.x * 256 + threadIdx.x;
    if (i4 >= 2097152) return;
    long i = (long)i4 * 4;
    const float* src;
    if (i < 4194304) {
        src = x + i;
    } else {
        long j = i - 4194304;
        int  w = (int)(j >> 20);
        long o = j & 1048575;
        src = (w == 0 ? wq : w == 1 ? wk : w == 2 ? wv : wo) + o;
    }
    float4 v = *(const float4*)src;
    short4 r;
    r.x = f2b(v.x); r.y = f2b(v.y); r.z = f2b(v.z); r.w = f2b(v.w);
    *(short4*)(ws + i) = r;
}

// ---------------------------------------------------------------------------
// Kernel 2: NT GEMM, 128x128 tile, BK=32, global_load_lds staging (m97-style).
// 256 threads = 4 waves (2x2), each wave 64x64 = 4x4 MFMA frags.
// fused=1: grid (32,24); blockIdx.y selects Wq/Wk/Wv -> Q/K/Vt (bf16).
// fused=0: grid (32,8); single B -> f32 row-major output.
// ---------------------------------------------------------------------------
__global__ __launch_bounds__(256, 2) void gemm128(
    const short* __restrict__ A,
    const short* __restrict__ B0, const short* __restrict__ B1,
    const short* __restrict__ B2,
    short* __restrict__ Oq, short* __restrict__ Ok, short* __restrict__ Ovt,
    float* __restrict__ Of, int fused)
{
    __shared__ __align__(16) short As[128 * 32];
    __shared__ __align__(16) short Bs[128 * 32];

    const int tid  = threadIdx.x;
    const int wave = tid >> 6;
    const int lane = tid & 63;
    const int r16  = lane & 15;
    const int g4   = lane >> 4;
    const int m0   = blockIdx.x * 128;

    const short* Bm;
    int n0, outmode;
    if (fused) {
        int mat = blockIdx.y >> 3;
        n0 = (blockIdx.y & 7) * 128;
        Bm = (mat == 0) ? B0 : (mat == 1) ? B1 : B2;
        outmode = (mat == 2) ? 1 : 0;     // Vt transposed, Q/K row layouts
    } else {
        n0 = blockIdx.y * 128;
        Bm = B0;
        outmode = 3;
    }
    short* Obf = (outmode == 1) ? Ovt : ((fused && (blockIdx.y >> 3) == 1) ? Ok : Oq);

    const int wm = wave & 1, wn = wave >> 1;

    f32x4 acc[4][4] = {};

    for (int k0 = 0; k0 < 1024; k0 += 32) {
        __syncthreads();
#pragma unroll
        for (int rr = 0; rr < 2; ++rr) {
            const int bidx = rr * 4096 + wave * 1024 + lane * 16;   // byte idx in tile
            const int row  = bidx >> 6;
            const int colb = bidx & 63;
            const char* ga = (const char*)A  + (long)(m0 + row) * 2048 + k0 * 2 + colb;
            const char* gb = (const char*)Bm + (long)(n0 + row) * 2048 + k0 * 2 + colb;
            char* la = (char*)As + rr * 4096 + wave * 1024;
            char* lb = (char*)Bs + rr * 4096 + wave * 1024;
            __builtin_amdgcn_global_load_lds((glb_u32*)ga, (lds_u32*)la, 16, 0, 0);
            __builtin_amdgcn_global_load_lds((glb_u32*)gb, (lds_u32*)lb, 16, 0, 0);
        }
        __syncthreads();

        short8 af[4], bf[4];
#pragma unroll
        for (int m = 0; m < 4; ++m)
            af[m] = *(const short8*)&As[(wm * 64 + m * 16 + r16) * 32 + g4 * 8];
#pragma unroll
        for (int n = 0; n < 4; ++n)
            bf[n] = *(const short8*)&Bs[(wn * 64 + n * 16 + r16) * 32 + g4 * 8];
#pragma unroll
        for (int m = 0; m < 4; ++m)
#pragma unroll
            for (int n = 0; n < 4; ++n)
                acc[m][n] = __builtin_amdgcn_mfma_f32_16x16x32_bf16(af[m], bf[n], acc[m][n], 0, 0, 0);
    }

#pragma unroll
    for (int m = 0; m < 4; ++m) {
#pragma unroll
        for (int n = 0; n < 4; ++n) {
            const int gcol = n0 + wn * 64 + n * 16 + r16;
#pragma unroll
            for (int j = 0; j < 4; ++j) {
                const int grow = m0 + wm * 64 + m * 16 + g4 * 4 + j;
                float v = acc[m][n][j];
                if (outmode == 3) {
                    Of[(long)grow * 1024 + gcol] = v;
                } else {
                    short s = f2b(v);
                    int b = grow >> 11, l = grow & 2047;
                    int h = gcol >> 6,  hd = gcol & 63;
                    long idx = (outmode == 0)
                        ? (((long)(b * HH + h) * LL + l) * HD + hd)
                        : (((long)(b * HH + h) * HD + hd) * LL + l);
                    Obf[idx] = s;
                }
            }
        }
    }
}

// ---------------------------------------------------------------------------
// Kernel 3: causal sparsemax attention, templated on NREG (row regs per lane;
// covers NREG*64 keys). Launched per qt-class. Block = (b,h) x 16 q-rows,
// 16 waves. tau init = rowmax - 1 (valid lower bound on tau*).
// ---------------------------------------------------------------------------
template <int NREG>
__global__ __launch_bounds__(1024, 4) void attn_sparsemax(
    const short* __restrict__ Q, const short* __restrict__ K,
    const short* __restrict__ Vt, short* __restrict__ AO, int qt_base)
{
    __shared__ __align__(16) float S[16][NREG * 64 + 4];
    __shared__ unsigned flags[64];

    const int tid  = threadIdx.x;
    const int wave = tid >> 6;
    const int lane = tid & 63;
    const int r16  = lane & 15;
    const int g4   = lane >> 4;

    const int bh = blockIdx.x & 31;
    const int qt = qt_base + (blockIdx.x >> 5);
    const int q0 = qt * 16;

    if (tid < 64) flags[tid] = 0;

    const long qbase = ((long)bh * LL + q0 + r16) * HD + g4 * 8;
    const short8 qa0 = *(const short8*)&Q[qbase];
    const short8 qa1 = *(const short8*)&Q[qbase + 32];

    // ---- Phase 1: QK^T ----
    for (int kt = wave; kt <= qt; kt += 16) {
        const long kbase = ((long)bh * LL + kt * 16 + r16) * HD + g4 * 8;
        short8 kb0 = *(const short8*)&K[kbase];
        short8 kb1 = *(const short8*)&K[kbase + 32];
        f32x4 sc = {};
        sc = __builtin_amdgcn_mfma_f32_16x16x32_bf16(qa0, kb0, sc, 0, 0, 0);
        sc = __builtin_amdgcn_mfma_f32_16x16x32_bf16(qa1, kb1, sc, 0, 0, 0);
        const int key = kt * 16 + r16;
#pragma unroll
        for (int j = 0; j < 4; ++j) {
            const int qrow = g4 * 4 + j;
            float v = sc[j] * 0.125f;
            if (key > q0 + qrow) v = -1e9f;
            S[qrow][key] = v;
        }
    }
    __syncthreads();

    // ---- Phase 2: sparsemax, wave r = row r ----
    {
        const int r   = wave;
        const int len = q0 + r + 1;
        float z[NREG];
        float m = -1e30f;
#pragma unroll
        for (int j = 0; j < NREG; ++j) {
            const int k = j * 64 + lane;
            float zz = S[r][k];
            zz = (k < len) ? zz : -1e30f;
            z[j] = zz;
            m = fmaxf(m, zz);
        }
#pragma unroll
        for (int o = 32; o; o >>= 1) m = fmaxf(m, __shfl_xor(m, o));

        float tau = m - 1.0f;          // tau* >= max - 1, Michelot from below
        int cprev = -1;
        for (int it = 0; it < 32; ++it) {
            float s = 0.f; int c = 0;
#pragma unroll
            for (int j = 0; j < NREG; ++j) {
                bool g = z[j] > tau;
                s += g ? z[j] : 0.f;
                c += g ? 1 : 0;
            }
#pragma unroll
            for (int o = 32; o; o >>= 1) {
                s += __shfl_xor(s, o);
                c += __shfl_xor(c, o);
            }
            float ntau = (s - 1.0f) / (float)c;
            if (c == cprev) break;     // support stable -> converged
            tau = ntau;
            cprev = c;
        }
#pragma unroll
        for (int j = 0; j < NREG; ++j) {
            const int k = j * 64 + lane;
            float p = fmaxf(z[j] - tau, 0.f);
            S[r][k] = p;
            unsigned long long mm = __ballot(p > 0.f);
            if (lane == 0) {
                if (mm & 0xffffffffull) atomicOr(&flags[2 * j], 1u);
                if (mm >> 32)           atomicOr(&flags[2 * j + 1], 1u);
            }
        }
    }
    __syncthreads();

    // ---- Phase 3: PV over flagged key tiles, waves 0..3 = d-tiles ----
    if (wave < 4) {
        const int nkt = (q0 + 16 + 31) >> 5;
        f32x4 acc = {};
        for (int kt = 0; kt < nkt; ++kt) {
            if (!flags[kt]) continue;
            const int kb = kt * 32 + g4 * 8;
            f32x4 p0 = *(const f32x4*)&S[r16][kb];
            f32x4 p1 = *(const f32x4*)&S[r16][kb + 4];
            short8 pa;
            pa[0] = f2b(p0[0]); pa[1] = f2b(p0[1]); pa[2] = f2b(p0[2]); pa[3] = f2b(p0[3]);
            pa[4] = f2b(p1[0]); pa[5] = f2b(p1[1]); pa[6] = f2b(p1[2]); pa[7] = f2b(p1[3]);
            short8 vb = *(const short8*)&Vt[((long)bh * HD + wave * 16 + r16) * LL + kb];
            acc = __builtin_amdgcn_mfma_f32_16x16x32_bf16(pa, vb, acc, 0, 0, 0);
        }
        const int b = bh >> 4, h = bh & 15;
#pragma unroll
        for (int j = 0; j < 4; ++j) {
            const int qrow = g4 * 4 + j;
            const long idx = ((long)b * LL + q0 + qrow) * DD + h * HD + wave * 16 + r16;
            AO[idx] = f2b(acc[j]);
        }
    }
}

// ---------------------------------------------------------------------------
extern "C" void kernel_launch(void* const* d_in, const int* in_sizes, int n_in,
                              void* d_out, int out_size, void* d_ws, size_t ws_size,
                              hipStream_t stream)
{
    const float* x  = (const float*)d_in[0];
    const float* wq = (const float*)d_in[1];
    const float* wk = (const float*)d_in[2];
    const float* wv = (const float*)d_in[3];
    const float* wo = (const float*)d_in[4];

    short* ws  = (short*)d_ws;
    short* xb  = ws;                     // 4,194,304 elems
    short* wqb = ws + 4194304;
    short* wkb = ws + 5242880;
    short* wvb = ws + 6291456;
    short* wob = ws + 7340032;
    short* Qb  = ws + 8388608;           // [B,H,L,HD]
    short* Kb  = ws + 12582912;          // [B,H,L,HD]
    short* Vtb = ws + 16777216;          // [B,H,HD,L]
    short* AOb = ws + 20971520;          // [B*L, D]

    cvt_all<<<8192, 256, 0, stream>>>(x, wq, wk, wv, wo, ws);

    gemm128<<<dim3(32, 24), 256, 0, stream>>>(xb, wqb, wkb, wvb,
                                              Qb, Kb, Vtb, (float*)nullptr, 1);

    attn_sparsemax<8 ><<<1024, 1024, 0, stream>>>(Qb, Kb, Vtb, AOb, 0);
    attn_sparsemax<16><<<1024, 1024, 0, stream>>>(Qb, Kb, Vtb, AOb, 32);
    attn_sparsemax<24><<<1024, 1024, 0, stream>>>(Qb, Kb, Vtb, AOb, 64);
    attn_sparsemax<32><<<1024, 1024, 0, stream>>>(Qb, Kb, Vtb, AOb, 96);

    gemm128<<<dim3(32, 8), 256, 0, stream>>>(AOb, wob, wob, wob,
                                             Qb, Kb, Vtb, (float*)d_out, 0);
}

// Round 7
// 360.123 us; speedup vs baseline: 1.6278x; 1.0491x over previous
//
#include <hip/hip_runtime.h>
#include <hip/hip_bf16.h>

#define LL 2048
#define DD 1024
#define HH 16
#define HD 64

typedef __attribute__((ext_vector_type(8))) short short8;
typedef __attribute__((ext_vector_type(4))) float f32x4;
typedef unsigned int u32;
typedef __attribute__((address_space(3))) u32 lds_u32;
typedef const __attribute__((address_space(1))) u32 glb_u32;

__device__ __forceinline__ short f2b(float f) {
    union { __hip_bfloat16 h; short s; } u;
    u.h = __float2bfloat16(f);
    return u.s;
}

// ---------------------------------------------------------------------------
// Kernel 1: convert x, Wq, Wk, Wv, Wo (f32) -> bf16 workspace (contiguous)
// ---------------------------------------------------------------------------
__global__ __launch_bounds__(256) void cvt_all(
    const float* __restrict__ x,  const float* __restrict__ wq,
    const float* __restrict__ wk, const float* __restrict__ wv,
    const float* __restrict__ wo, short* __restrict__ ws)
{
    int i4 = blockIdx.x * 256 + threadIdx.x;
    if (i4 >= 2097152) return;
    long i = (long)i4 * 4;
    const float* src;
    if (i < 4194304) {
        src = x + i;
    } else {
        long j = i - 4194304;
        int  w = (int)(j >> 20);
        long o = j & 1048575;
        src = (w == 0 ? wq : w == 1 ? wk : w == 2 ? wv : wo) + o;
    }
    float4 v = *(const float4*)src;
    short4 r;
    r.x = f2b(v.x); r.y = f2b(v.y); r.z = f2b(v.z); r.w = f2b(v.w);
    *(short4*)(ws + i) = r;
}

// ---------------------------------------------------------------------------
// Kernel 2: NT GEMM, 128x128 tile, BK=32, global_load_lds staging (m97-style).
// 256 threads = 4 waves (2x2), each wave 64x64 = 4x4 MFMA frags.
// fused=1: grid (32,24); blockIdx.y selects Wq/Wk/Wv -> Q/K/Vt (bf16).
// fused=0: grid (32,8); single B -> f32 row-major output.
// ---------------------------------------------------------------------------
__global__ __launch_bounds__(256, 2) void gemm128(
    const short* __restrict__ A,
    const short* __restrict__ B0, const short* __restrict__ B1,
    const short* __restrict__ B2,
    short* __restrict__ Oq, short* __restrict__ Ok, short* __restrict__ Ovt,
    float* __restrict__ Of, int fused)
{
    __shared__ __align__(16) short As[128 * 32];
    __shared__ __align__(16) short Bs[128 * 32];

    const int tid  = threadIdx.x;
    const int wave = tid >> 6;
    const int lane = tid & 63;
    const int r16  = lane & 15;
    const int g4   = lane >> 4;
    const int m0   = blockIdx.x * 128;

    const short* Bm;
    int n0, outmode;
    if (fused) {
        int mat = blockIdx.y >> 3;
        n0 = (blockIdx.y & 7) * 128;
        Bm = (mat == 0) ? B0 : (mat == 1) ? B1 : B2;
        outmode = (mat == 2) ? 1 : 0;     // Vt transposed, Q/K row layouts
    } else {
        n0 = blockIdx.y * 128;
        Bm = B0;
        outmode = 3;
    }
    short* Obf = (outmode == 1) ? Ovt : ((fused && (blockIdx.y >> 3) == 1) ? Ok : Oq);

    const int wm = wave & 1, wn = wave >> 1;

    f32x4 acc[4][4] = {};

    for (int k0 = 0; k0 < 1024; k0 += 32) {
        __syncthreads();
#pragma unroll
        for (int rr = 0; rr < 2; ++rr) {
            const int bidx = rr * 4096 + wave * 1024 + lane * 16;   // byte idx in tile
            const int row  = bidx >> 6;
            const int colb = bidx & 63;
            const char* ga = (const char*)A  + (long)(m0 + row) * 2048 + k0 * 2 + colb;
            const char* gb = (const char*)Bm + (long)(n0 + row) * 2048 + k0 * 2 + colb;
            char* la = (char*)As + rr * 4096 + wave * 1024;
            char* lb = (char*)Bs + rr * 4096 + wave * 1024;
            __builtin_amdgcn_global_load_lds((glb_u32*)ga, (lds_u32*)la, 16, 0, 0);
            __builtin_amdgcn_global_load_lds((glb_u32*)gb, (lds_u32*)lb, 16, 0, 0);
        }
        __syncthreads();

        short8 af[4], bf[4];
#pragma unroll
        for (int m = 0; m < 4; ++m)
            af[m] = *(const short8*)&As[(wm * 64 + m * 16 + r16) * 32 + g4 * 8];
#pragma unroll
        for (int n = 0; n < 4; ++n)
            bf[n] = *(const short8*)&Bs[(wn * 64 + n * 16 + r16) * 32 + g4 * 8];
#pragma unroll
        for (int m = 0; m < 4; ++m)
#pragma unroll
            for (int n = 0; n < 4; ++n)
                acc[m][n] = __builtin_amdgcn_mfma_f32_16x16x32_bf16(af[m], bf[n], acc[m][n], 0, 0, 0);
    }

#pragma unroll
    for (int m = 0; m < 4; ++m) {
#pragma unroll
        for (int n = 0; n < 4; ++n) {
            const int gcol = n0 + wn * 64 + n * 16 + r16;
#pragma unroll
            for (int j = 0; j < 4; ++j) {
                const int grow = m0 + wm * 64 + m * 16 + g4 * 4 + j;
                float v = acc[m][n][j];
                if (outmode == 3) {
                    Of[(long)grow * 1024 + gcol] = v;
                } else {
                    short s = f2b(v);
                    int b = grow >> 11, l = grow & 2047;
                    int h = gcol >> 6,  hd = gcol & 63;
                    long idx = (outmode == 0)
                        ? (((long)(b * HH + h) * LL + l) * HD + hd)
                        : (((long)(b * HH + h) * HD + hd) * LL + l);
                    Obf[idx] = s;
                }
            }
        }
    }
}

// ---------------------------------------------------------------------------
// Kernel 3: causal sparsemax attention, templated on NREG (row f32 per lane;
// covers NREG*64 keys). Launched per qt-class. Block = (b,h) x 16 q-rows,
// 16 waves.
// Phase 2: z held in f32x4 regs (asm-pinned vs LDS re-materialization),
//          tau init = rowmax-1 (valid lower bound), vectorized b128 LDS IO.
// Phase 3: all 16 waves = (d-tile, key-quarter); partials reduced via Pred.
// ---------------------------------------------------------------------------
template <int NREG>
__global__ __launch_bounds__(1024, 4) void attn_sparsemax(
    const short* __restrict__ Q, const short* __restrict__ K,
    const short* __restrict__ Vt, short* __restrict__ AO, int qt_base)
{
    constexpr int NV = NREG / 4;                 // f32x4 chunks per lane
    __shared__ __align__(16) float S[16][NREG * 64 + 4];
    __shared__ __align__(16) f32x4 Pred[16][64];
    __shared__ unsigned flags[64];

    const int tid  = threadIdx.x;
    const int wave = tid >> 6;
    const int lane = tid & 63;
    const int r16  = lane & 15;
    const int g4   = lane >> 4;

    const int bh = blockIdx.x & 31;
    const int qt = qt_base + (blockIdx.x >> 5);
    const int q0 = qt * 16;

    if (tid < 64) flags[tid] = 0;

    const long qbase = ((long)bh * LL + q0 + r16) * HD + g4 * 8;
    const short8 qa0 = *(const short8*)&Q[qbase];
    const short8 qa1 = *(const short8*)&Q[qbase + 32];

    // ---- Phase 1: QK^T ----
    for (int kt = wave; kt <= qt; kt += 16) {
        const long kbase = ((long)bh * LL + kt * 16 + r16) * HD + g4 * 8;
        short8 kb0 = *(const short8*)&K[kbase];
        short8 kb1 = *(const short8*)&K[kbase + 32];
        f32x4 sc = {};
        sc = __builtin_amdgcn_mfma_f32_16x16x32_bf16(qa0, kb0, sc, 0, 0, 0);
        sc = __builtin_amdgcn_mfma_f32_16x16x32_bf16(qa1, kb1, sc, 0, 0, 0);
        const int key = kt * 16 + r16;
#pragma unroll
        for (int j = 0; j < 4; ++j) {
            const int qrow = g4 * 4 + j;
            float v = sc[j] * 0.125f;
            if (key > q0 + qrow) v = -1e9f;
            S[qrow][key] = v;
        }
    }
    __syncthreads();

    // ---- Phase 2: sparsemax, wave r = row r; z register-resident ----
    {
        const int r   = wave;
        const int len = q0 + r + 1;
        f32x4 z4[NV];
        float m = -1e30f;
#pragma unroll
        for (int j = 0; j < NV; ++j) {
            f32x4 v = *(const f32x4*)&S[r][j * 256 + lane * 4];
            const int kb = j * 256 + lane * 4;
#pragma unroll
            for (int e = 0; e < 4; ++e) {
                float zz = (kb + e < len) ? v[e] : -1e30f;   // guard poison tail
                v[e] = zz;
                m = fmaxf(m, zz);
            }
            z4[j] = v;
            asm volatile("" : "+v"(z4[j]));   // pin in VGPRs: forbid LDS re-read
        }
#pragma unroll
        for (int o = 32; o; o >>= 1) m = fmaxf(m, __shfl_xor(m, o));

        float tau = m - 1.0f;          // tau* >= max - 1, Michelot from below
        int cprev = -1;
        for (int it = 0; it < 24; ++it) {
            float s = 0.f; int c = 0;
#pragma unroll
            for (int j = 0; j < NV; ++j) {
#pragma unroll
                for (int e = 0; e < 4; ++e) {
                    bool g = z4[j][e] > tau;
                    s += g ? z4[j][e] : 0.f;
                    c += g ? 1 : 0;
                }
            }
#pragma unroll
            for (int o = 32; o; o >>= 1) {
                s += __shfl_xor(s, o);
                c += __shfl_xor(c, o);
            }
            if (c == cprev) break;     // support stable -> converged
            tau = (s - 1.0f) / (float)c;
            cprev = c;
        }
#pragma unroll
        for (int j = 0; j < NV; ++j) {
            f32x4 p;
#pragma unroll
            for (int e = 0; e < 4; ++e) p[e] = fmaxf(z4[j][e] - tau, 0.f);
            *(f32x4*)&S[r][j * 256 + lane * 4] = p;
            bool nz = (p[0] > 0.f) | (p[1] > 0.f) | (p[2] > 0.f) | (p[3] > 0.f);
            unsigned long long mm = __ballot(nz);
            if (lane < 8) {            // tile t=lane covers keys (j*8+t)*32..+31
                if ((mm >> (lane * 8)) & 0xffull) atomicOr(&flags[j * 8 + lane], 1u);
            }
        }
    }
    __syncthreads();

    // ---- Phase 3: PV, wave = (d-tile, key-quarter); reduce via Pred ----
    {
        const int dt = wave & 3;
        const int kq = wave >> 2;
        const int nkt = (q0 + 16 + 31) >> 5;
        f32x4 acc = {};
        for (int kt = kq; kt < nkt; kt += 4) {
            if (!flags[kt]) continue;
            const int kb = kt * 32 + g4 * 8;
            f32x4 p0 = *(const f32x4*)&S[r16][kb];
            f32x4 p1 = *(const f32x4*)&S[r16][kb + 4];
            short8 pa;
            pa[0] = f2b(p0[0]); pa[1] = f2b(p0[1]); pa[2] = f2b(p0[2]); pa[3] = f2b(p0[3]);
            pa[4] = f2b(p1[0]); pa[5] = f2b(p1[1]); pa[6] = f2b(p1[2]); pa[7] = f2b(p1[3]);
            short8 vb = *(const short8*)&Vt[((long)bh * HD + dt * 16 + r16) * LL + kb];
            acc = __builtin_amdgcn_mfma_f32_16x16x32_bf16(pa, vb, acc, 0, 0, 0);
        }
        Pred[wave][lane] = acc;
    }
    __syncthreads();
    if (wave < 4) {
        f32x4 a = Pred[wave][lane];
        {
            f32x4 b0 = Pred[wave + 4][lane];
            f32x4 b1 = Pred[wave + 8][lane];
            f32x4 b2 = Pred[wave + 12][lane];
#pragma unroll
            for (int e = 0; e < 4; ++e) a[e] += b0[e] + b1[e] + b2[e];
        }
        const int b = bh >> 4, h = bh & 15;
#pragma unroll
        for (int j = 0; j < 4; ++j) {
            const int qrow = g4 * 4 + j;
            const long idx = ((long)b * LL + q0 + qrow) * DD + h * HD + wave * 16 + r16;
            AO[idx] = f2b(a[j]);
        }
    }
}

// ---------------------------------------------------------------------------
extern "C" void kernel_launch(void* const* d_in, const int* in_sizes, int n_in,
                              void* d_out, int out_size, void* d_ws, size_t ws_size,
                              hipStream_t stream)
{
    const float* x  = (const float*)d_in[0];
    const float* wq = (const float*)d_in[1];
    const float* wk = (const float*)d_in[2];
    const float* wv = (const float*)d_in[3];
    const float* wo = (const float*)d_in[4];

    short* ws  = (short*)d_ws;
    short* xb  = ws;                     // 4,194,304 elems
    short* wqb = ws + 4194304;
    short* wkb = ws + 5242880;
    short* wvb = ws + 6291456;
    short* wob = ws + 7340032;
    short* Qb  = ws + 8388608;           // [B,H,L,HD]
    short* Kb  = ws + 12582912;          // [B,H,L,HD]
    short* Vtb = ws + 16777216;          // [B,H,HD,L]
    short* AOb = ws + 20971520;          // [B*L, D]

    cvt_all<<<8192, 256, 0, stream>>>(x, wq, wk, wv, wo, ws);

    gemm128<<<dim3(32, 24), 256, 0, stream>>>(xb, wqb, wkb, wvb,
                                              Qb, Kb, Vtb, (float*)nullptr, 1);

    attn_sparsemax<8 ><<<1024, 1024, 0, stream>>>(Qb, Kb, Vtb, AOb, 0);
    attn_sparsemax<16><<<1024, 1024, 0, stream>>>(Qb, Kb, Vtb, AOb, 32);
    attn_sparsemax<24><<<1024, 1024, 0, stream>>>(Qb, Kb, Vtb, AOb, 64);
    attn_sparsemax<32><<<1024, 1024, 0, stream>>>(Qb, Kb, Vtb, AOb, 96);

    gemm128<<<dim3(32, 8), 256, 0, stream>>>(AOb, wob, wob, wob,
                                             Qb, Kb, Vtb, (float*)d_out, 0);
}

// Round 9
// 348.164 us; speedup vs baseline: 1.6837x; 1.0343x over previous
//
#include <hip/hip_runtime.h>
#include <hip/hip_bf16.h>

#define LL 2048
#define DD 1024
#define HH 16
#define HD 64

typedef __attribute__((ext_vector_type(8))) short short8;
typedef __attribute__((ext_vector_type(4))) float f32x4;
typedef unsigned int u32;
typedef __attribute__((address_space(3))) u32 lds_u32;
typedef const __attribute__((address_space(1))) u32 glb_u32;

__device__ __forceinline__ short f2b(float f) {
    union { __hip_bfloat16 h; short s; } u;
    u.h = __float2bfloat16(f);
    return u.s;
}

// ---------------------------------------------------------------------------
// Kernel 1: convert x, Wq, Wk, Wv, Wo (f32) -> bf16 workspace (contiguous)
// ---------------------------------------------------------------------------
__global__ __launch_bounds__(256) void cvt_all(
    const float* __restrict__ x,  const float* __restrict__ wq,
    const float* __restrict__ wk, const float* __restrict__ wv,
    const float* __restrict__ wo, short* __restrict__ ws)
{
    int i4 = blockIdx.x * 256 + threadIdx.x;
    if (i4 >= 2097152) return;
    long i = (long)i4 * 4;
    const float* src;
    if (i < 4194304) {
        src = x + i;
    } else {
        long j = i - 4194304;
        int  w = (int)(j >> 20);
        long o = j & 1048575;
        src = (w == 0 ? wq : w == 1 ? wk : w == 2 ? wv : wo) + o;
    }
    float4 v = *(const float4*)src;
    short4 r;
    r.x = f2b(v.x); r.y = f2b(v.y); r.z = f2b(v.z); r.w = f2b(v.w);
    *(short4*)(ws + i) = r;
}

// ---------------------------------------------------------------------------
// Kernel 2: NT GEMM, 128x128 tile, BK=32, global_load_lds staging (m97-style).
// 256 threads = 4 waves (2x2), each wave 64x64 = 4x4 MFMA frags.
// fused=1: grid (32,24); blockIdx.y selects Wq/Wk/Wv -> Q/K/Vt (bf16).
// fused=0: grid (32,8); single B -> f32 row-major output.
// ---------------------------------------------------------------------------
__global__ __launch_bounds__(256, 2) void gemm128(
    const short* __restrict__ A,
    const short* __restrict__ B0, const short* __restrict__ B1,
    const short* __restrict__ B2,
    short* __restrict__ Oq, short* __restrict__ Ok, short* __restrict__ Ovt,
    float* __restrict__ Of, int fused)
{
    __shared__ __align__(16) short As[128 * 32];
    __shared__ __align__(16) short Bs[128 * 32];

    const int tid  = threadIdx.x;
    const int wave = tid >> 6;
    const int lane = tid & 63;
    const int r16  = lane & 15;
    const int g4   = lane >> 4;
    const int m0   = blockIdx.x * 128;

    const short* Bm;
    int n0, outmode;
    if (fused) {
        int mat = blockIdx.y >> 3;
        n0 = (blockIdx.y & 7) * 128;
        Bm = (mat == 0) ? B0 : (mat == 1) ? B1 : B2;
        outmode = (mat == 2) ? 1 : 0;     // Vt transposed, Q/K row layouts
    } else {
        n0 = blockIdx.y * 128;
        Bm = B0;
        outmode = 3;
    }
    short* Obf = (outmode == 1) ? Ovt : ((fused && (blockIdx.y >> 3) == 1) ? Ok : Oq);

    const int wm = wave & 1, wn = wave >> 1;

    f32x4 acc[4][4] = {};

    for (int k0 = 0; k0 < 1024; k0 += 32) {
        __syncthreads();
#pragma unroll
        for (int rr = 0; rr < 2; ++rr) {
            const int bidx = rr * 4096 + wave * 1024 + lane * 16;   // byte idx in tile
            const int row  = bidx >> 6;
            const int colb = bidx & 63;
            const char* ga = (const char*)A  + (long)(m0 + row) * 2048 + k0 * 2 + colb;
            const char* gb = (const char*)Bm + (long)(n0 + row) * 2048 + k0 * 2 + colb;
            char* la = (char*)As + rr * 4096 + wave * 1024;
            char* lb = (char*)Bs + rr * 4096 + wave * 1024;
            __builtin_amdgcn_global_load_lds((glb_u32*)ga, (lds_u32*)la, 16, 0, 0);
            __builtin_amdgcn_global_load_lds((glb_u32*)gb, (lds_u32*)lb, 16, 0, 0);
        }
        __syncthreads();

        short8 af[4], bf[4];
#pragma unroll
        for (int m = 0; m < 4; ++m)
            af[m] = *(const short8*)&As[(wm * 64 + m * 16 + r16) * 32 + g4 * 8];
#pragma unroll
        for (int n = 0; n < 4; ++n)
            bf[n] = *(const short8*)&Bs[(wn * 64 + n * 16 + r16) * 32 + g4 * 8];
#pragma unroll
        for (int m = 0; m < 4; ++m)
#pragma unroll
            for (int n = 0; n < 4; ++n)
                acc[m][n] = __builtin_amdgcn_mfma_f32_16x16x32_bf16(af[m], bf[n], acc[m][n], 0, 0, 0);
    }

#pragma unroll
    for (int m = 0; m < 4; ++m) {
#pragma unroll
        for (int n = 0; n < 4; ++n) {
            const int gcol = n0 + wn * 64 + n * 16 + r16;
#pragma unroll
            for (int j = 0; j < 4; ++j) {
                const int grow = m0 + wm * 64 + m * 16 + g4 * 4 + j;
                float v = acc[m][n][j];
                if (outmode == 3) {
                    Of[(long)grow * 1024 + gcol] = v;
                } else {
                    short s = f2b(v);
                    int b = grow >> 11, l = grow & 2047;
                    int h = gcol >> 6,  hd = gcol & 63;
                    long idx = (outmode == 0)
                        ? (((long)(b * HH + h) * LL + l) * HD + hd)
                        : (((long)(b * HH + h) * HD + hd) * LL + l);
                    Obf[idx] = s;
                }
            }
        }
    }
}

// ---------------------------------------------------------------------------
// Kernel 3: causal sparsemax attention, templated on NREG (row f32 per lane;
// covers NREG*64 keys). Block = (b,h) x 16 q-rows, 16 waves.
// Phase 2 (exact, sort-based): tau* >= rowmax-1, so support is inside
//   C0 = {z > rowmax-1} (|C0| ~ 28 for Gaussian scores). Extract C0 into a
//   64-slot LDS row buffer, bitonic-sort across the wave's 64 lanes,
//   prefix-scan, k-select -> exact reference tau in one pass.
//   Rows with |C0| > 64 (P ~ 1e-11) fall back to Michelot from tau0.
// Phase 3: all 16 waves = (d-tile, key-quarter); partials reduced by reusing
//   S's front as the reduction buffer (S is dead after PV reads).
// ---------------------------------------------------------------------------
template <int NREG>
__global__ __launch_bounds__(1024, (NREG <= 16 ? 8 : 4)) void attn_sparsemax(
    const short* __restrict__ Q, const short* __restrict__ K,
    const short* __restrict__ Vt, short* __restrict__ AO, int qt_base)
{
    constexpr int NV = NREG / 4;                 // f32x4 chunks per lane
    __shared__ __align__(16) float S[16][NREG * 64 + 4];
    __shared__ float cand[16][64];
    __shared__ int   ccnt[16];
    __shared__ unsigned flags[64];

    const int tid  = threadIdx.x;
    const int wave = tid >> 6;
    const int lane = tid & 63;
    const int r16  = lane & 15;
    const int g4   = lane >> 4;

    const int bh = blockIdx.x & 31;
    const int qt = qt_base + (blockIdx.x >> 5);
    const int q0 = qt * 16;

    if (tid < 64) flags[tid] = 0;
    if (tid < 16) ccnt[tid] = 0;

    const long qbase = ((long)bh * LL + q0 + r16) * HD + g4 * 8;
    const short8 qa0 = *(const short8*)&Q[qbase];
    const short8 qa1 = *(const short8*)&Q[qbase + 32];

    // ---- Phase 1: QK^T ----
    for (int kt = wave; kt <= qt; kt += 16) {
        const long kbase = ((long)bh * LL + kt * 16 + r16) * HD + g4 * 8;
        short8 kb0 = *(const short8*)&K[kbase];
        short8 kb1 = *(const short8*)&K[kbase + 32];
        f32x4 sc = {};
        sc = __builtin_amdgcn_mfma_f32_16x16x32_bf16(qa0, kb0, sc, 0, 0, 0);
        sc = __builtin_amdgcn_mfma_f32_16x16x32_bf16(qa1, kb1, sc, 0, 0, 0);
        const int key = kt * 16 + r16;
#pragma unroll
        for (int j = 0; j < 4; ++j) {
            const int qrow = g4 * 4 + j;
            float v = sc[j] * 0.125f;
            if (key > q0 + qrow) v = -1e9f;
            S[qrow][key] = v;
        }
    }
    __syncthreads();

    // ---- Phase 2: exact sparsemax, wave r = row r ----
    {
        const int r   = wave;
        const int len = q0 + r + 1;
        f32x4 z4[NV];
        float m = -1e30f;
#pragma unroll
        for (int j = 0; j < NV; ++j) {
            f32x4 v = *(const f32x4*)&S[r][j * 256 + lane * 4];
            const int kb = j * 256 + lane * 4;
#pragma unroll
            for (int e = 0; e < 4; ++e) {
                float zz = (kb + e < len) ? v[e] : -1e30f;   // guard poison tail
                v[e] = zz;
                m = fmaxf(m, zz);
            }
            z4[j] = v;
            asm volatile("" : "+v"(z4[j]));   // pin in VGPRs: forbid LDS re-read
        }
#pragma unroll
        for (int o = 32; o; o >>= 1) m = fmaxf(m, __shfl_xor(m, o));

        const float tau0 = m - 1.0f;         // tau* >= rowmax - 1
        // extraction scan: push candidates, count via cross-lane reduce
        int myc = 0;
#pragma unroll
        for (int j = 0; j < NV; ++j) {
#pragma unroll
            for (int e = 0; e < 4; ++e) {
                float v = z4[j][e];
                if (v > tau0) {
                    int pos = atomicAdd(&ccnt[r], 1);
                    if (pos < 64) cand[r][pos] = v;
                    myc++;
                }
            }
        }
#pragma unroll
        for (int o = 32; o; o >>= 1) myc += __shfl_xor(myc, o);
        const int cnt = myc;

        float tau;
        if (cnt <= 64) {
            // exact sort-based tau on candidates (== reference on full array)
            float w = (lane < cnt) ? -cand[r][lane] : 1e30f;  // ascending(-v)
#pragma unroll
            for (int k = 2; k <= 64; k <<= 1) {
#pragma unroll
                for (int j = k >> 1; j > 0; j >>= 1) {
                    float p = __shfl_xor(w, j);
                    bool keepMin = (((lane & j) == 0) == ((lane & k) == 0));
                    w = keepMin ? fminf(w, p) : fmaxf(w, p);
                }
            }
            float v = -w;                     // descending sorted candidates
            float cs = v;                     // inclusive prefix sum
#pragma unroll
            for (int o = 1; o < 64; o <<= 1) {
                float t = __shfl_up(cs, o);
                if (lane >= o) cs += t;
            }
            bool cond = (lane < cnt) && (1.0f + (float)(lane + 1) * v > cs);
            unsigned long long mk = __ballot(cond);
            int kk = __popcll(mk);            // support size (>=1 always)
            float csk = __shfl(cs, kk - 1);
            tau = (csk - 1.0f) / (float)kk;
        } else {
            // fallback: Michelot from tau0 on the full register array
            tau = tau0;
            int cprev = -1;
            for (int it = 0; it < 32; ++it) {
                float s = 0.f; int c = 0;
#pragma unroll
                for (int j = 0; j < NV; ++j) {
#pragma unroll
                    for (int e = 0; e < 4; ++e) {
                        bool g = z4[j][e] > tau;
                        s += g ? z4[j][e] : 0.f;
                        c += g ? 1 : 0;
                    }
                }
#pragma unroll
                for (int o = 32; o; o >>= 1) {
                    s += __shfl_xor(s, o);
                    c += __shfl_xor(c, o);
                }
                if (c == cprev) break;
                tau = (s - 1.0f) / (float)c;
                cprev = c;
            }
        }
        // write back p = max(z - tau, 0), flag nonzero 32-key tiles
#pragma unroll
        for (int j = 0; j < NV; ++j) {
            f32x4 p;
#pragma unroll
            for (int e = 0; e < 4; ++e) p[e] = fmaxf(z4[j][e] - tau, 0.f);
            *(f32x4*)&S[r][j * 256 + lane * 4] = p;
            bool nz = (p[0] > 0.f) | (p[1] > 0.f) | (p[2] > 0.f) | (p[3] > 0.f);
            unsigned long long mm = __ballot(nz);
            if (lane < 8) {            // tile t=lane covers keys (j*8+t)*32..+31
                if ((mm >> (lane * 8)) & 0xffull) atomicOr(&flags[j * 8 + lane], 1u);
            }
        }
    }
    __syncthreads();

    // ---- Phase 3: PV, wave = (d-tile, key-quarter); reduce via S-front ----
    float* Sf = &S[0][0];
    {
        const int dt = wave & 3;
        const int kq = wave >> 2;
        const int nkt = (q0 + 16 + 31) >> 5;
        f32x4 acc = {};
        for (int kt = kq; kt < nkt; kt += 4) {
            if (!flags[kt]) continue;
            const int kb = kt * 32 + g4 * 8;
            f32x4 p0 = *(const f32x4*)&S[r16][kb];
            f32x4 p1 = *(const f32x4*)&S[r16][kb + 4];
            short8 pa;
            pa[0] = f2b(p0[0]); pa[1] = f2b(p0[1]); pa[2] = f2b(p0[2]); pa[3] = f2b(p0[3]);
            pa[4] = f2b(p1[0]); pa[5] = f2b(p1[1]); pa[6] = f2b(p1[2]); pa[7] = f2b(p1[3]);
            short8 vb = *(const short8*)&Vt[((long)bh * HD + dt * 16 + r16) * LL + kb];
            acc = __builtin_amdgcn_mfma_f32_16x16x32_bf16(pa, vb, acc, 0, 0, 0);
        }
        __syncthreads();                              // all P reads of S done
        *(f32x4*)&Sf[(wave * 64 + lane) * 4] = acc;   // reuse S as [16][64] f32x4
    }
    __syncthreads();
    if (wave < 4) {
        f32x4 a  = *(const f32x4*)&Sf[(wave * 64 + lane) * 4];
        f32x4 b0 = *(const f32x4*)&Sf[((wave + 4) * 64 + lane) * 4];
        f32x4 b1 = *(const f32x4*)&Sf[((wave + 8) * 64 + lane) * 4];
        f32x4 b2 = *(const f32x4*)&Sf[((wave + 12) * 64 + lane) * 4];
#pragma unroll
        for (int e = 0; e < 4; ++e) a[e] += b0[e] + b1[e] + b2[e];
        const int b = bh >> 4, h = bh & 15;
#pragma unroll
        for (int j = 0; j < 4; ++j) {
            const int qrow = g4 * 4 + j;
            const long idx = ((long)b * LL + q0 + qrow) * DD + h * HD + wave * 16 + r16;
            AO[idx] = f2b(a[j]);
        }
    }
}

// ---------------------------------------------------------------------------
extern "C" void kernel_launch(void* const* d_in, const int* in_sizes, int n_in,
                              void* d_out, int out_size, void* d_ws, size_t ws_size,
                              hipStream_t stream)
{
    const float* x  = (const float*)d_in[0];
    const float* wq = (const float*)d_in[1];
    const float* wk = (const float*)d_in[2];
    const float* wv = (const float*)d_in[3];
    const float* wo = (const float*)d_in[4];

    short* ws  = (short*)d_ws;
    short* xb  = ws;                     // 4,194,304 elems
    short* wqb = ws + 4194304;
    short* wkb = ws + 5242880;
    short* wvb = ws + 6291456;
    short* wob = ws + 7340032;
    short* Qb  = ws + 8388608;           // [B,H,L,HD]
    short* Kb  = ws + 12582912;          // [B,H,L,HD]
    short* Vtb = ws + 16777216;          // [B,H,HD,L]
    short* AOb = ws + 20971520;          // [B*L, D]

    cvt_all<<<8192, 256, 0, stream>>>(x, wq, wk, wv, wo, ws);

    gemm128<<<dim3(32, 24), 256, 0, stream>>>(xb, wqb, wkb, wvb,
                                              Qb, Kb, Vtb, (float*)nullptr, 1);

    attn_sparsemax<8 ><<<1024, 1024, 0, stream>>>(Qb, Kb, Vtb, AOb, 0);
    attn_sparsemax<16><<<1024, 1024, 0, stream>>>(Qb, Kb, Vtb, AOb, 32);
    attn_sparsemax<24><<<1024, 1024, 0, stream>>>(Qb, Kb, Vtb, AOb, 64);
    attn_sparsemax<32><<<1024, 1024, 0, stream>>>(Qb, Kb, Vtb, AOb, 96);

    gemm128<<<dim3(32, 8), 256, 0, stream>>>(AOb, wob, wob, wob,
                                             Qb, Kb, Vtb, (float*)d_out, 0);
}